// Round 2
// baseline (848.243 us; speedup 1.0000x reference)
//
#include <hip/hip_runtime.h>
#include <cstdint>

#define T_TOK 8192
#define D_DIM 1024
#define E_EXP 8
#define F_DIM 3584
#define NROW  (2 * T_TOK)   // total (token, expert-slot) assignment rows

typedef __attribute__((ext_vector_type(8))) __bf16 bf16x8;
typedef __attribute__((ext_vector_type(4))) float f32x4;

// -------- async global->LDS: 16B/lane, LDS dest = wave-uniform base + lane*16 --------
__device__ __forceinline__ void gload16(const void* g, void* l) {
    __builtin_amdgcn_global_load_lds(
        (const __attribute__((address_space(1))) void*)(g),
        (__attribute__((address_space(3))) void*)(l),
        16, 0, 0);
}

// -------- fp32 -> bf16 conversion (8 elems/thread) --------
__global__ void cvt_kernel(const float* __restrict__ in, __bf16* __restrict__ out, long n) {
    long i = ((long)blockIdx.x * blockDim.x + threadIdx.x) * 8;
    if (i >= n) return;
    const float4 f0 = *(const float4*)(in + i);
    const float4 f1 = *(const float4*)(in + i + 4);
    bf16x8 o;
    o[0] = (__bf16)f0.x; o[1] = (__bf16)f0.y; o[2] = (__bf16)f0.z; o[3] = (__bf16)f0.w;
    o[4] = (__bf16)f1.x; o[5] = (__bf16)f1.y; o[6] = (__bf16)f1.z; o[7] = (__bf16)f1.w;
    *(bf16x8*)(out + i) = o;
}

// -------- routing --------
__global__ void route_kernel(const float* __restrict__ rl, int* cnt,
                             int* __restrict__ eidx, float* __restrict__ ewgt) {
    int t = blockIdx.x * blockDim.x + threadIdx.x;
    if (t >= T_TOK) return;
    float l[8];
#pragma unroll
    for (int e = 0; e < 8; ++e) l[e] = rl[t * 8 + e];
    int i0 = 0; float v0 = l[0];
    int i1 = -1; float v1 = -1e30f;
#pragma unroll
    for (int e = 1; e < 8; ++e) {
        if (l[e] > v0) { v1 = v0; i1 = i0; v0 = l[e]; i0 = e; }
        else if (l[e] > v1) { v1 = l[e]; i1 = e; }
    }
    float wsec = 1.f / (1.f + __expf(v0 - v1));
    eidx[2 * t] = i0; eidx[2 * t + 1] = i1;
    ewgt[2 * t] = 1.f - wsec; ewgt[2 * t + 1] = wsec;
    atomicAdd(&cnt[i0], 1); atomicAdd(&cnt[i1], 1);
}

__global__ void scan_kernel(const int* __restrict__ cnt, int* __restrict__ offs) {
    if (threadIdx.x == 0) {
        int a = 0;
        for (int e = 0; e < E_EXP; ++e) { offs[e] = a; a += cnt[e]; }
        offs[E_EXP] = a;
    }
}

__global__ void assign_kernel(const int* __restrict__ eidx, const float* __restrict__ ewgt,
                              const int* __restrict__ offs, int* cnt2,
                              int* __restrict__ tok, int* __restrict__ rowOf) {
    int t = blockIdx.x * blockDim.x + threadIdx.x;
    if (t >= T_TOK) return;
#pragma unroll
    for (int s = 0; s < 2; ++s) {
        int e = eidx[2 * t + s];
        int pos = atomicAdd(&cnt2[e], 1);
        int row = offs[e] + pos;
        tok[row] = t;
        rowOf[2 * t + s] = row;
    }
}

// ---- chunk mapping for a 128x64 bf16 half-tile (16KB), st_16x32-swizzled ----
// LDS-linear chunk c (16B units, c in [0,1024)) -> tile (row, elem-col) of the
// pre-swizzled global source. Read side applies the same XOR -> round-trips.
__device__ __forceinline__ int chunk_row(int c) { return ((c >> 7) << 4) | ((c >> 2) & 15); }
__device__ __forceinline__ int chunk_col(int c) {
    return ((c >> 6) & 1) * 32 + (((c & 3) * 8) ^ (((c >> 5) & 1) << 4));
}

#define G1_NT 16   // K-tiles of 64 over D=1024
#define G2_NT 56   // K-tiles of 64 over F=3584

// =========================================================================
// GEMM1: gathered xb rows [256] x interleaved concat(w1,w3) [256 cols] per tile.
// B concat-row rb: 16-col block (rb>>4); even block -> w1, odd -> w3, both at
// f = nt*128 + (rb>>5 ... (blk>>1))*16 + (rb&15). So wave-local frag ni even =
// gate, ni odd = up at the same f -> in-wave silu fusion.
// 8 waves (2m x 4n), BK=64, deep 2-buffer pipeline with counted vmcnt.
// =========================================================================
__global__ __launch_bounds__(512, 1)
void gemm1_kernel(const __bf16* __restrict__ xb,
                  const __bf16* __restrict__ w1b,
                  const __bf16* __restrict__ w3b,
                  const int* __restrict__ tok_of_row,
                  const int* __restrict__ offs,
                  __bf16* __restrict__ h) {
    const int e  = blockIdx.z;
    const int mt = blockIdx.y;
    const int nt = blockIdx.x;
    const int row0 = offs[e];
    const int rows = offs[e + 1] - row0;
    if (mt * 256 >= rows) return;

    __shared__ __align__(16) __bf16 Ash[2][2][8192];  // [buf][half][128x64]
    __shared__ __align__(16) __bf16 Bsh[2][2][8192];

    const int tid = threadIdx.x;
    const int wave = tid >> 6, lane = tid & 63;
    const int wm = wave >> 2, wn = wave & 3;
    const int fr = lane & 15, fg = lane >> 4;

    // staging source pointers (4 A-chunks + 4 B-chunks per thread per K-tile)
    const __bf16* srcA[2][2];
    const __bf16* srcB[2][2];
#pragma unroll
    for (int half = 0; half < 2; ++half)
#pragma unroll
        for (int j = 0; j < 2; ++j) {
            const int c = tid + j * 512;
            const int r = chunk_row(c), k = chunk_col(c);
            int ra = mt * 256 + half * 128 + r;
            ra = min(ra, rows - 1);
            srcA[half][j] = xb + (long)tok_of_row[row0 + ra] * D_DIM + k;
            const int rb = half * 128 + r;
            const int blk = rb >> 4;
            const int f = nt * 128 + (blk >> 1) * 16 + (rb & 15);
            const __bf16* wsel = (blk & 1) ? w3b : w1b;
            srcB[half][j] = wsel + ((long)e * F_DIM + f) * D_DIM + k;
        }

    auto stage = [&](int buf, int kt) {   // 8 global_load_lds per call
        const int k0 = kt * 64;
#pragma unroll
        for (int half = 0; half < 2; ++half)
#pragma unroll
            for (int j = 0; j < 2; ++j) {
                gload16(srcA[half][j] + k0, &Ash[buf][half][(j * 512 + wave * 64) * 8]);
                gload16(srcB[half][j] + k0, &Bsh[buf][half][(j * 512 + wave * 64) * 8]);
            }
    };

    const int abase = fr * 32 + ((fg * 8) ^ ((fr & 8) << 1));  // swizzled frag base
    f32x4 acc[8][4] = {};

    stage(0, 0);
    stage(1, 1);
    for (int t = 0; t < G1_NT; ++t) {
        const int cur = t & 1;
        if (t + 1 < G1_NT) asm volatile("s_waitcnt vmcnt(8)" ::: "memory");
        else               asm volatile("s_waitcnt vmcnt(0)" ::: "memory");
        __builtin_amdgcn_sched_barrier(0);
        __builtin_amdgcn_s_barrier();
        __builtin_amdgcn_sched_barrier(0);
        const __bf16* Ab = &Ash[cur][wm][abase];
        const __bf16* Bb = &Bsh[cur][wn >> 1][abase];
        bf16x8 bfr[4][2];
#pragma unroll
        for (int ni = 0; ni < 4; ++ni)
#pragma unroll
            for (int kk = 0; kk < 2; ++kk)
                bfr[ni][kk] = *(const bf16x8*)(Bb + (((wn & 1) * 4 + ni) * 2 + kk) * 512);
#pragma unroll
        for (int mi = 0; mi < 8; ++mi) {
            const bf16x8 a0 = *(const bf16x8*)(Ab + (mi * 2 + 0) * 512);
            const bf16x8 a1 = *(const bf16x8*)(Ab + (mi * 2 + 1) * 512);
#pragma unroll
            for (int ni = 0; ni < 4; ++ni) {
                acc[mi][ni] = __builtin_amdgcn_mfma_f32_16x16x32_bf16(a0, bfr[ni][0], acc[mi][ni], 0, 0, 0);
                acc[mi][ni] = __builtin_amdgcn_mfma_f32_16x16x32_bf16(a1, bfr[ni][1], acc[mi][ni], 0, 0, 0);
            }
        }
        __builtin_amdgcn_sched_barrier(0);
        __builtin_amdgcn_s_barrier();
        __builtin_amdgcn_sched_barrier(0);
        if (t + 2 < G1_NT) stage(cur, t + 2);
    }

    // epilogue: h = silu(gate) * up.  C/D: col = lane&15, row = fg*4 + reg
#pragma unroll
    for (int mi = 0; mi < 8; ++mi) {
#pragma unroll
        for (int reg = 0; reg < 4; ++reg) {
            const int lm = mt * 256 + wm * 128 + mi * 16 + fg * 4 + reg;
            if (lm < rows) {
                const long hrow = (long)(row0 + lm) * F_DIM;
#pragma unroll
                for (int b = 0; b < 2; ++b) {
                    const float g = acc[mi][2 * b][reg];
                    const float u = acc[mi][2 * b + 1][reg];
                    const float s = g / (1.f + __expf(-g));
                    h[hrow + nt * 128 + (wn * 2 + b) * 16 + fr] = (__bf16)(s * u);
                }
            }
        }
    }
}

// =========================================================================
// GEMM2: h[rows, F] x w2[e]^T [D, F] -> o2[row, d] (bf16, unweighted, no atomics)
// =========================================================================
__global__ __launch_bounds__(512, 1)
void gemm2_kernel(const __bf16* __restrict__ h,
                  const __bf16* __restrict__ w2b,
                  const int* __restrict__ offs,
                  __bf16* __restrict__ o2) {
    const int e  = blockIdx.z;
    const int mt = blockIdx.y;
    const int nt = blockIdx.x;   // D/256 = 4
    const int row0 = offs[e];
    const int rows = offs[e + 1] - row0;
    if (mt * 256 >= rows) return;

    __shared__ __align__(16) __bf16 Ash[2][2][8192];
    __shared__ __align__(16) __bf16 Bsh[2][2][8192];

    const int tid = threadIdx.x;
    const int wave = tid >> 6, lane = tid & 63;
    const int wm = wave >> 2, wn = wave & 3;
    const int fr = lane & 15, fg = lane >> 4;

    const __bf16* srcA[2][2];
    const __bf16* srcB[2][2];
#pragma unroll
    for (int half = 0; half < 2; ++half)
#pragma unroll
        for (int j = 0; j < 2; ++j) {
            const int c = tid + j * 512;
            const int r = chunk_row(c), k = chunk_col(c);
            int ra = mt * 256 + half * 128 + r;
            ra = min(ra, rows - 1);
            srcA[half][j] = h + (long)(row0 + ra) * F_DIM + k;
            const int rb = half * 128 + r;
            srcB[half][j] = w2b + ((long)e * D_DIM + nt * 256 + rb) * F_DIM + k;
        }

    auto stage = [&](int buf, int kt) {
        const int k0 = kt * 64;
#pragma unroll
        for (int half = 0; half < 2; ++half)
#pragma unroll
            for (int j = 0; j < 2; ++j) {
                gload16(srcA[half][j] + k0, &Ash[buf][half][(j * 512 + wave * 64) * 8]);
                gload16(srcB[half][j] + k0, &Bsh[buf][half][(j * 512 + wave * 64) * 8]);
            }
    };

    const int abase = fr * 32 + ((fg * 8) ^ ((fr & 8) << 1));
    f32x4 acc[8][4] = {};

    stage(0, 0);
    stage(1, 1);
    for (int t = 0; t < G2_NT; ++t) {
        const int cur = t & 1;
        if (t + 1 < G2_NT) asm volatile("s_waitcnt vmcnt(8)" ::: "memory");
        else               asm volatile("s_waitcnt vmcnt(0)" ::: "memory");
        __builtin_amdgcn_sched_barrier(0);
        __builtin_amdgcn_s_barrier();
        __builtin_amdgcn_sched_barrier(0);
        const __bf16* Ab = &Ash[cur][wm][abase];
        const __bf16* Bb = &Bsh[cur][wn >> 1][abase];
        bf16x8 bfr[4][2];
#pragma unroll
        for (int ni = 0; ni < 4; ++ni)
#pragma unroll
            for (int kk = 0; kk < 2; ++kk)
                bfr[ni][kk] = *(const bf16x8*)(Bb + (((wn & 1) * 4 + ni) * 2 + kk) * 512);
#pragma unroll
        for (int mi = 0; mi < 8; ++mi) {
            const bf16x8 a0 = *(const bf16x8*)(Ab + (mi * 2 + 0) * 512);
            const bf16x8 a1 = *(const bf16x8*)(Ab + (mi * 2 + 1) * 512);
#pragma unroll
            for (int ni = 0; ni < 4; ++ni) {
                acc[mi][ni] = __builtin_amdgcn_mfma_f32_16x16x32_bf16(a0, bfr[ni][0], acc[mi][ni], 0, 0, 0);
                acc[mi][ni] = __builtin_amdgcn_mfma_f32_16x16x32_bf16(a1, bfr[ni][1], acc[mi][ni], 0, 0, 0);
            }
        }
        __builtin_amdgcn_sched_barrier(0);
        __builtin_amdgcn_s_barrier();
        __builtin_amdgcn_sched_barrier(0);
        if (t + 2 < G2_NT) stage(cur, t + 2);
    }

#pragma unroll
    for (int mi = 0; mi < 8; ++mi) {
#pragma unroll
        for (int reg = 0; reg < 4; ++reg) {
            const int lm = mt * 256 + wm * 128 + mi * 16 + fg * 4 + reg;
            if (lm < rows) {
                const long obase = (long)(row0 + lm) * D_DIM + nt * 256 + wn * 64 + fr;
#pragma unroll
                for (int ni = 0; ni < 4; ++ni)
                    o2[obase + ni * 16] = (__bf16)acc[mi][ni][reg];
            }
        }
    }
}

// -------- combine: out[t] = w0*o2[row0] + w1*o2[row1]  (8 cols/thread) --------
__global__ void combine_kernel(const __bf16* __restrict__ o2, const int* __restrict__ rowOf,
                               const float* __restrict__ ewgt, float* __restrict__ out) {
    const int idx = blockIdx.x * blockDim.x + threadIdx.x;  // T * D/8
    const int t = idx >> 7;
    const int j = (idx & 127) * 8;
    const long r0 = rowOf[2 * t], r1 = rowOf[2 * t + 1];
    const float w0 = ewgt[2 * t], w1 = ewgt[2 * t + 1];
    const bf16x8 a = *(const bf16x8*)(o2 + r0 * D_DIM + j);
    const bf16x8 b = *(const bf16x8*)(o2 + r1 * D_DIM + j);
    float r[8];
#pragma unroll
    for (int q = 0; q < 8; ++q) r[q] = w0 * (float)a[q] + w1 * (float)b[q];
    float4* ob = (float4*)(out + (long)t * D_DIM + j);
    ob[0] = make_float4(r[0], r[1], r[2], r[3]);
    ob[1] = make_float4(r[4], r[5], r[6], r[7]);
}

// =========================================================================
extern "C" void kernel_launch(void* const* d_in, const int* in_sizes, int n_in,
                              void* d_out, int out_size, void* d_ws, size_t ws_size,
                              hipStream_t stream) {
    const float* x  = (const float*)d_in[0];
    const float* w1 = (const float*)d_in[1];
    const float* w3 = (const float*)d_in[2];
    const float* w2 = (const float*)d_in[3];
    const float* rl = (const float*)d_in[4];
    float* out = (float*)d_out;

    char* ws = (char*)d_ws;
    size_t off = 0;
    auto alloc = [&](size_t bytes) {
        void* p = ws + off;
        off += (bytes + 255) & ~(size_t)255;
        return p;
    };
    __bf16* xb   = (__bf16*)alloc((size_t)T_TOK * D_DIM * 2);
    __bf16* w1b  = (__bf16*)alloc((size_t)E_EXP * F_DIM * D_DIM * 2);
    __bf16* w3b  = (__bf16*)alloc((size_t)E_EXP * F_DIM * D_DIM * 2);
    __bf16* w2b  = (__bf16*)alloc((size_t)E_EXP * D_DIM * F_DIM * 2);
    __bf16* h    = (__bf16*)alloc((size_t)NROW * F_DIM * 2);
    __bf16* o2   = (__bf16*)alloc((size_t)NROW * D_DIM * 2);
    int*   tok   = (int*)alloc(NROW * 4);
    int*   rowOf = (int*)alloc(NROW * 4);
    int*   eidx  = (int*)alloc(NROW * 4);
    float* ewgt  = (float*)alloc(NROW * 4);
    int*   cnt1  = (int*)alloc(64);
    int*   cnt2  = (int*)alloc(64);
    int*   offs  = (int*)alloc(64);

    hipMemsetAsync(cnt1, 0, 64, stream);
    hipMemsetAsync(cnt2, 0, 64, stream);

    {
        long n = (long)T_TOK * D_DIM;
        cvt_kernel<<<(int)(n / 8 / 256), 256, 0, stream>>>(x, xb, n);
        n = (long)E_EXP * F_DIM * D_DIM;
        const int blks = (int)(n / 8 / 256);
        cvt_kernel<<<blks, 256, 0, stream>>>(w1, w1b, n);
        cvt_kernel<<<blks, 256, 0, stream>>>(w3, w3b, n);
        cvt_kernel<<<blks, 256, 0, stream>>>(w2, w2b, n);
    }

    route_kernel<<<T_TOK / 256, 256, 0, stream>>>(rl, cnt1, eidx, ewgt);
    scan_kernel<<<1, 64, 0, stream>>>(cnt1, offs);
    assign_kernel<<<T_TOK / 256, 256, 0, stream>>>(eidx, ewgt, offs, cnt2, tok, rowOf);

    dim3 g1(F_DIM / 128, T_TOK / 256, E_EXP);   // (28, 32, 8); tail tiles early-exit
    gemm1_kernel<<<g1, 512, 0, stream>>>(xb, w1b, w3b, tok, offs, h);

    dim3 g2(D_DIM / 256, T_TOK / 256, E_EXP);   // (4, 32, 8)
    gemm2_kernel<<<g2, 512, 0, stream>>>(h, w2b, offs, o2);

    combine_kernel<<<T_TOK * (D_DIM / 8) / 256, 256, 0, stream>>>(o2, rowOf, ewgt, out);
}

// Round 3
// 709.825 us; speedup vs baseline: 1.1950x; 1.1950x over previous
//
#include <hip/hip_runtime.h>
#include <cstdint>

#define T_TOK 8192
#define D_DIM 1024
#define E_EXP 8
#define F_DIM 3584
#define NROW  (2 * T_TOK)   // total (token, expert-slot) assignment rows

typedef __attribute__((ext_vector_type(8))) __bf16 bf16x8;
typedef __attribute__((ext_vector_type(4))) float f32x4;

// -------- async global->LDS: 16B/lane, LDS dest = wave-uniform base + lane*16 --------
__device__ __forceinline__ void gload16(const void* g, void* l) {
    __builtin_amdgcn_global_load_lds(
        (const __attribute__((address_space(1))) void*)(g),
        (__attribute__((address_space(3))) void*)(l),
        16, 0, 0);
}

// -------- bijective XCD-aware block swizzle (m204 variant) --------
__device__ __forceinline__ int xcd_swz(int bid, int nwg) {
    const int nx = 8;
    const int q = nwg / nx, r = nwg % nx;
    const int xcd = bid % nx, lid = bid / nx;
    return (xcd < r ? xcd * (q + 1) : r * (q + 1) + (xcd - r) * q) + lid;
}

// -------- fp32 -> bf16 conversion (8 elems/thread) --------
__global__ void cvt_kernel(const float* __restrict__ in, __bf16* __restrict__ out, long n) {
    long i = ((long)blockIdx.x * blockDim.x + threadIdx.x) * 8;
    if (i >= n) return;
    const float4 f0 = *(const float4*)(in + i);
    const float4 f1 = *(const float4*)(in + i + 4);
    bf16x8 o;
    o[0] = (__bf16)f0.x; o[1] = (__bf16)f0.y; o[2] = (__bf16)f0.z; o[3] = (__bf16)f0.w;
    o[4] = (__bf16)f1.x; o[5] = (__bf16)f1.y; o[6] = (__bf16)f1.z; o[7] = (__bf16)f1.w;
    *(bf16x8*)(out + i) = o;
}

// -------- routing --------
__global__ void route_kernel(const float* __restrict__ rl, int* cnt,
                             int* __restrict__ eidx, float* __restrict__ ewgt) {
    int t = blockIdx.x * blockDim.x + threadIdx.x;
    if (t >= T_TOK) return;
    float l[8];
#pragma unroll
    for (int e = 0; e < 8; ++e) l[e] = rl[t * 8 + e];
    int i0 = 0; float v0 = l[0];
    int i1 = -1; float v1 = -1e30f;
#pragma unroll
    for (int e = 1; e < 8; ++e) {
        if (l[e] > v0) { v1 = v0; i1 = i0; v0 = l[e]; i0 = e; }
        else if (l[e] > v1) { v1 = l[e]; i1 = e; }
    }
    float wsec = 1.f / (1.f + __expf(v0 - v1));
    eidx[2 * t] = i0; eidx[2 * t + 1] = i1;
    ewgt[2 * t] = 1.f - wsec; ewgt[2 * t + 1] = wsec;
    atomicAdd(&cnt[i0], 1); atomicAdd(&cnt[i1], 1);
}

__global__ void scan_kernel(const int* __restrict__ cnt, int* __restrict__ offs) {
    if (threadIdx.x == 0) {
        int a = 0;
        for (int e = 0; e < E_EXP; ++e) { offs[e] = a; a += cnt[e]; }
        offs[E_EXP] = a;
    }
}

__global__ void assign_kernel(const int* __restrict__ eidx, const float* __restrict__ ewgt,
                              const int* __restrict__ offs, int* cnt2,
                              int* __restrict__ tok, int* __restrict__ rowOf) {
    int t = blockIdx.x * blockDim.x + threadIdx.x;
    if (t >= T_TOK) return;
#pragma unroll
    for (int s = 0; s < 2; ++s) {
        int e = eidx[2 * t + s];
        int pos = atomicAdd(&cnt2[e], 1);
        int row = offs[e] + pos;
        tok[row] = t;
        rowOf[2 * t + s] = row;
    }
}

// ---- chunk mapping for a 128x64 bf16 half-tile (16KB), st_16x32-swizzled ----
__device__ __forceinline__ int chunk_row(int c) { return ((c >> 7) << 4) | ((c >> 2) & 15); }
__device__ __forceinline__ int chunk_col(int c) {
    return ((c >> 6) & 1) * 32 + (((c & 3) * 8) ^ (((c >> 5) & 1) << 4));
}

// =========================================================================
// 8-phase deep-pipelined K-loop (T2+T3+T4+T5).  256x256 tile, BK=64, 8 waves.
// Stage order per iter i (computing K-tiles u=2i [buf0], v=2i+1 [buf1]):
//   P1: A0(v)  P2: A1(v)  P3: B0(u+2)  P4: B1(u+2)  [vmcnt gate]
//   P5: A0(u+2) P6: A1(u+2) P7: B0(v+2) P8: B1(v+2) [vmcnt gate]
// Buffer-free proof: B of a tile is fully read in its first phase; A by its
// 4th; each stage lands only after the corresponding close-barrier.
// vmcnt(4): at each gate the 2 newest half-tile stages (4 loads) may fly.
// =========================================================================
template <int NT>
__device__ __forceinline__ void moe_pipeline(
    const __bf16* const (&srcA)[2][2], const __bf16* const (&srcB)[2][2],
    __bf16 (&Ash)[2][2][8192], __bf16 (&Bsh)[2][2][8192],
    int wave, int abase, int wm, int bh, int bsel, f32x4 (&acc)[8][4])
{
    auto stA = [&](int buf, int kt, int h) {
        const int k0 = kt * 64;
        gload16(srcA[h][0] + k0, &Ash[buf][h][(0 * 512 + wave * 64) * 8]);
        gload16(srcA[h][1] + k0, &Ash[buf][h][(1 * 512 + wave * 64) * 8]);
    };
    auto stB = [&](int buf, int kt, int h) {
        const int k0 = kt * 64;
        gload16(srcB[h][0] + k0, &Bsh[buf][h][(0 * 512 + wave * 64) * 8]);
        gload16(srcB[h][1] + k0, &Bsh[buf][h][(1 * 512 + wave * 64) * 8]);
    };

    bf16x8 bfr[4][2];
    bf16x8 a0, a1, a2, a3;

#define LD_A(Ab, q) \
    a0 = *(const bf16x8*)((Ab) + ((2*(q)) * 2 + 0) * 512); \
    a1 = *(const bf16x8*)((Ab) + ((2*(q)) * 2 + 1) * 512); \
    a2 = *(const bf16x8*)((Ab) + ((2*(q)+1) * 2 + 0) * 512); \
    a3 = *(const bf16x8*)((Ab) + ((2*(q)+1) * 2 + 1) * 512);

#define LD_B(Bb) \
    _Pragma("unroll") for (int ni = 0; ni < 4; ++ni) { \
        bfr[ni][0] = *(const bf16x8*)((Bb) + ((bsel * 4 + ni) * 2 + 0) * 512); \
        bfr[ni][1] = *(const bf16x8*)((Bb) + ((bsel * 4 + ni) * 2 + 1) * 512); \
    }

#define MFMA_Q(q) \
    _Pragma("unroll") for (int ni = 0; ni < 4; ++ni) { \
        acc[2*(q)][ni]   = __builtin_amdgcn_mfma_f32_16x16x32_bf16(a0, bfr[ni][0], acc[2*(q)][ni], 0, 0, 0); \
        acc[2*(q)][ni]   = __builtin_amdgcn_mfma_f32_16x16x32_bf16(a1, bfr[ni][1], acc[2*(q)][ni], 0, 0, 0); \
        acc[2*(q)+1][ni] = __builtin_amdgcn_mfma_f32_16x16x32_bf16(a2, bfr[ni][0], acc[2*(q)+1][ni], 0, 0, 0); \
        acc[2*(q)+1][ni] = __builtin_amdgcn_mfma_f32_16x16x32_bf16(a3, bfr[ni][1], acc[2*(q)+1][ni], 0, 0, 0); \
    }

#define PH_OPEN() \
    __builtin_amdgcn_sched_barrier(0); \
    __builtin_amdgcn_s_barrier(); \
    asm volatile("s_waitcnt lgkmcnt(0)" ::: "memory"); \
    __builtin_amdgcn_sched_barrier(0); \
    __builtin_amdgcn_s_setprio(1);

#define PH_CLOSE() \
    __builtin_amdgcn_s_setprio(0); \
    __builtin_amdgcn_sched_barrier(0); \
    __builtin_amdgcn_s_barrier(); \
    __builtin_amdgcn_sched_barrier(0);

#define PH_CLOSE_G(lastf) \
    __builtin_amdgcn_s_setprio(0); \
    __builtin_amdgcn_sched_barrier(0); \
    if (lastf) { asm volatile("s_waitcnt vmcnt(0)" ::: "memory"); } \
    else       { asm volatile("s_waitcnt vmcnt(4)" ::: "memory"); } \
    __builtin_amdgcn_s_barrier(); \
    __builtin_amdgcn_sched_barrier(0);

    // prologue: tile0 fully, tile1 B-halves; gate so tile0 has landed
    stA(0, 0, 0); stA(0, 0, 1); stB(0, 0, 0); stB(0, 0, 1);
    stB(1, 1, 0); stB(1, 1, 1);
    asm volatile("s_waitcnt vmcnt(4)" ::: "memory");
    __builtin_amdgcn_s_barrier();

    const __bf16* AbE = &Ash[0][wm][abase];
    const __bf16* BbE = &Bsh[0][bh][abase];
    const __bf16* AbO = &Ash[1][wm][abase];
    const __bf16* BbO = &Bsh[1][bh][abase];

    for (int it = 0; it < NT / 2; ++it) {
        const int kv = 2 * it + 1;
        const bool last = (it == NT / 2 - 1);
        // ---- K-tile even (buf0) ----
        LD_A(AbE, 0) LD_B(BbE)
        stA(1, kv, 0);
        PH_OPEN() MFMA_Q(0) PH_CLOSE()
        LD_A(AbE, 1)
        stA(1, kv, 1);
        PH_OPEN() MFMA_Q(1) PH_CLOSE()
        LD_A(AbE, 2)
        if (!last) stB(0, kv + 1, 0);
        PH_OPEN() MFMA_Q(2) PH_CLOSE()
        LD_A(AbE, 3)
        if (!last) stB(0, kv + 1, 1);
        PH_OPEN() MFMA_Q(3) PH_CLOSE_G(last)
        // ---- K-tile odd (buf1) ----
        LD_A(AbO, 0) LD_B(BbO)
        if (!last) stA(0, kv + 1, 0);
        PH_OPEN() MFMA_Q(0) PH_CLOSE()
        LD_A(AbO, 1)
        if (!last) stA(0, kv + 1, 1);
        PH_OPEN() MFMA_Q(1) PH_CLOSE()
        LD_A(AbO, 2)
        if (!last) stB(1, kv + 2, 0);
        PH_OPEN() MFMA_Q(2) PH_CLOSE()
        LD_A(AbO, 3)
        if (!last) stB(1, kv + 2, 1);
        PH_OPEN() MFMA_Q(3) PH_CLOSE_G(last)
    }
#undef LD_A
#undef LD_B
#undef MFMA_Q
#undef PH_OPEN
#undef PH_CLOSE
#undef PH_CLOSE_G
}

// =========================================================================
// GEMM1: gathered xb rows [256] x interleaved concat(w1,w3) [256 B-rows].
// =========================================================================
__global__ __launch_bounds__(512, 1)
void gemm1_kernel(const __bf16* __restrict__ xb,
                  const __bf16* __restrict__ w1b,
                  const __bf16* __restrict__ w3b,
                  const int* __restrict__ tok_of_row,
                  const int* __restrict__ offs,
                  __bf16* __restrict__ h) {
    const int NX = F_DIM / 128, NY = T_TOK / 256;
    const int nwg = NX * NY * E_EXP;
    int w = xcd_swz(blockIdx.x + NX * (blockIdx.y + NY * blockIdx.z), nwg);
    const int nt = w % NX; w /= NX;
    const int mt = w % NY; w /= NY;
    const int e = w;
    const int row0 = offs[e];
    const int rows = offs[e + 1] - row0;
    if (mt * 256 >= rows) return;

    __shared__ __align__(16) __bf16 Ash[2][2][8192];
    __shared__ __align__(16) __bf16 Bsh[2][2][8192];

    const int tid = threadIdx.x;
    const int wave = tid >> 6, lane = tid & 63;
    const int wm = wave >> 2, wn = wave & 3;
    const int fr = lane & 15, fg = lane >> 4;

    const __bf16* srcA[2][2];
    const __bf16* srcB[2][2];
#pragma unroll
    for (int half = 0; half < 2; ++half)
#pragma unroll
        for (int j = 0; j < 2; ++j) {
            const int c = tid + j * 512;
            const int r = chunk_row(c), k = chunk_col(c);
            int ra = mt * 256 + half * 128 + r;
            ra = min(ra, rows - 1);
            srcA[half][j] = xb + (long)tok_of_row[row0 + ra] * D_DIM + k;
            const int rb = half * 128 + r;
            const int blk = rb >> 4;
            const int f = nt * 128 + (blk >> 1) * 16 + (rb & 15);
            const __bf16* wsel = (blk & 1) ? w3b : w1b;
            srcB[half][j] = wsel + ((long)e * F_DIM + f) * D_DIM + k;
        }

    const int abase = fr * 32 + ((fg * 8) ^ ((fr & 8) << 1));
    f32x4 acc[8][4] = {};

    moe_pipeline<16>(srcA, srcB, Ash, Bsh, wave, abase, wm, wn >> 1, wn & 1, acc);

    // epilogue: h = silu(gate) * up.  C/D: col = lane&15, row = fg*4 + reg
#pragma unroll
    for (int mi = 0; mi < 8; ++mi) {
#pragma unroll
        for (int reg = 0; reg < 4; ++reg) {
            const int lm = mt * 256 + wm * 128 + mi * 16 + fg * 4 + reg;
            if (lm < rows) {
                const long hrow = (long)(row0 + lm) * F_DIM;
#pragma unroll
                for (int b = 0; b < 2; ++b) {
                    const float g = acc[mi][2 * b][reg];
                    const float u = acc[mi][2 * b + 1][reg];
                    const float s = g / (1.f + __expf(-g));
                    h[hrow + nt * 128 + (wn * 2 + b) * 16 + fr] = (__bf16)(s * u);
                }
            }
        }
    }
}

// =========================================================================
// GEMM2 (split-K x4): h[rows, F-slice] x w2[e]^T -> bf16 partial p[s]
// =========================================================================
__global__ __launch_bounds__(512, 1)
void gemm2_kernel(const __bf16* __restrict__ h,
                  const __bf16* __restrict__ w2b,
                  const int* __restrict__ offs,
                  __bf16* __restrict__ o2p) {
    const int NX = D_DIM / 256, NY = T_TOK / 256, NZ = E_EXP * 4;
    const int nwg = NX * NY * NZ;
    int w = xcd_swz(blockIdx.x + NX * (blockIdx.y + NY * blockIdx.z), nwg);
    const int nt = w % NX; w /= NX;
    const int mt = w % NY; w /= NY;
    const int e = w >> 2, ks = w & 3;
    const int row0 = offs[e];
    const int rows = offs[e + 1] - row0;
    if (mt * 256 >= rows) return;

    __shared__ __align__(16) __bf16 Ash[2][2][8192];
    __shared__ __align__(16) __bf16 Bsh[2][2][8192];

    const int tid = threadIdx.x;
    const int wave = tid >> 6, lane = tid & 63;
    const int wm = wave >> 2, wn = wave & 3;
    const int fr = lane & 15, fg = lane >> 4;
    const int kofs = ks * 14 * 64;   // 896-col K slice

    const __bf16* srcA[2][2];
    const __bf16* srcB[2][2];
#pragma unroll
    for (int half = 0; half < 2; ++half)
#pragma unroll
        for (int j = 0; j < 2; ++j) {
            const int c = tid + j * 512;
            const int r = chunk_row(c), k = chunk_col(c) + kofs;
            int ra = mt * 256 + half * 128 + r;
            ra = min(ra, rows - 1);
            srcA[half][j] = h + (long)(row0 + ra) * F_DIM + k;
            const int rb = half * 128 + r;
            srcB[half][j] = w2b + ((long)e * D_DIM + nt * 256 + rb) * F_DIM + k;
        }

    const int abase = fr * 32 + ((fg * 8) ^ ((fr & 8) << 1));
    f32x4 acc[8][4] = {};

    moe_pipeline<14>(srcA, srcB, Ash, Bsh, wave, abase, wm, wn >> 1, wn & 1, acc);

    __bf16* ps = o2p + (long)ks * NROW * D_DIM;
#pragma unroll
    for (int mi = 0; mi < 8; ++mi) {
#pragma unroll
        for (int reg = 0; reg < 4; ++reg) {
            const int lm = mt * 256 + wm * 128 + mi * 16 + fg * 4 + reg;
            if (lm < rows) {
                const long obase = (long)(row0 + lm) * D_DIM + nt * 256 + wn * 64 + fr;
#pragma unroll
                for (int ni = 0; ni < 4; ++ni)
                    ps[obase + ni * 16] = (__bf16)acc[mi][ni][reg];
            }
        }
    }
}

// -------- combine: out[t] = w0*sum_s ps[r0] + w1*sum_s ps[r1] --------
__global__ void combine_kernel(const __bf16* __restrict__ o2p, const int* __restrict__ rowOf,
                               const float* __restrict__ ewgt, float* __restrict__ out) {
    const int idx = blockIdx.x * blockDim.x + threadIdx.x;  // T * D/8
    const int t = idx >> 7;
    const int j = (idx & 127) * 8;
    const long r0 = rowOf[2 * t], r1 = rowOf[2 * t + 1];
    const float w0 = ewgt[2 * t], w1 = ewgt[2 * t + 1];
    float r[8] = {0, 0, 0, 0, 0, 0, 0, 0};
#pragma unroll
    for (int s = 0; s < 4; ++s) {
        const bf16x8 a = *(const bf16x8*)(o2p + ((long)s * NROW + r0) * D_DIM + j);
        const bf16x8 b = *(const bf16x8*)(o2p + ((long)s * NROW + r1) * D_DIM + j);
#pragma unroll
        for (int q = 0; q < 8; ++q) r[q] += w0 * (float)a[q] + w1 * (float)b[q];
    }
    float4* ob = (float4*)(out + (long)t * D_DIM + j);
    ob[0] = make_float4(r[0], r[1], r[2], r[3]);
    ob[1] = make_float4(r[4], r[5], r[6], r[7]);
}

// =========================================================================
extern "C" void kernel_launch(void* const* d_in, const int* in_sizes, int n_in,
                              void* d_out, int out_size, void* d_ws, size_t ws_size,
                              hipStream_t stream) {
    const float* x  = (const float*)d_in[0];
    const float* w1 = (const float*)d_in[1];
    const float* w3 = (const float*)d_in[2];
    const float* w2 = (const float*)d_in[3];
    const float* rl = (const float*)d_in[4];
    float* out = (float*)d_out;

    char* ws = (char*)d_ws;
    size_t off = 0;
    auto alloc = [&](size_t bytes) {
        void* p = ws + off;
        off += (bytes + 255) & ~(size_t)255;
        return p;
    };
    // NOTE: o2p (4 bf16 split-K partials, 134.2 MB) aliases [xb, w1b, w3b]
    // (exactly 16.8+58.7+58.7 MB) — all three are dead once gemm1 completes.
    __bf16* xb   = (__bf16*)alloc((size_t)T_TOK * D_DIM * 2);
    __bf16* w1b  = (__bf16*)alloc((size_t)E_EXP * F_DIM * D_DIM * 2);
    __bf16* w3b  = (__bf16*)alloc((size_t)E_EXP * F_DIM * D_DIM * 2);
    __bf16* w2b  = (__bf16*)alloc((size_t)E_EXP * D_DIM * F_DIM * 2);
    __bf16* h    = (__bf16*)alloc((size_t)NROW * F_DIM * 2);
    int*   tok   = (int*)alloc(NROW * 4);
    int*   rowOf = (int*)alloc(NROW * 4);
    int*   eidx  = (int*)alloc(NROW * 4);
    float* ewgt  = (float*)alloc(NROW * 4);
    int*   cnt1  = (int*)alloc(64);
    int*   cnt2  = (int*)alloc(64);
    int*   offs  = (int*)alloc(64);
    __bf16* o2p  = xb;   // alias (see note)

    hipMemsetAsync(cnt1, 0, 64, stream);
    hipMemsetAsync(cnt2, 0, 64, stream);

    {
        long n = (long)T_TOK * D_DIM;
        cvt_kernel<<<(int)(n / 8 / 256), 256, 0, stream>>>(x, xb, n);
        n = (long)E_EXP * F_DIM * D_DIM;
        const int blks = (int)(n / 8 / 256);
        cvt_kernel<<<blks, 256, 0, stream>>>(w1, w1b, n);
        cvt_kernel<<<blks, 256, 0, stream>>>(w3, w3b, n);
        cvt_kernel<<<blks, 256, 0, stream>>>(w2, w2b, n);
    }

    route_kernel<<<T_TOK / 256, 256, 0, stream>>>(rl, cnt1, eidx, ewgt);
    scan_kernel<<<1, 64, 0, stream>>>(cnt1, offs);
    assign_kernel<<<T_TOK / 256, 256, 0, stream>>>(eidx, ewgt, offs, cnt2, tok, rowOf);

    dim3 g1(F_DIM / 128, T_TOK / 256, E_EXP);       // (28, 32, 8)
    gemm1_kernel<<<g1, 512, 0, stream>>>(xb, w1b, w3b, tok, offs, h);

    dim3 g2(D_DIM / 256, T_TOK / 256, E_EXP * 4);   // (4, 32, 32) split-K x4
    gemm2_kernel<<<g2, 512, 0, stream>>>(h, w2b, offs, o2p);

    combine_kernel<<<T_TOK * (D_DIM / 8) / 256, 256, 0, stream>>>(o2p, rowOf, ewgt, out);
}